// Round 9
// baseline (134.188 us; speedup 1.0000x reference)
//
#include <hip/hip_runtime.h>
#include <math.h>

// CircleLoss fused, R9: fully wave-autonomous MFMA kernel -- ZERO barriers,
// ZERO LDS in the hot loop. R8 post-mortem: per-tile block-wide barriers
// phase-locked all waves (MFMA phase / VALU phase alternate, pipes idle in
// turn) -> 4x stall. Fix: A and B fragments loaded DIRECTLY global->register
// (xhi is 2MB, L1/L2-resident; the frag pattern 16rows x 64B coalesces
// perfectly), waves self-pace via vmcnt, MFMA+VALU+VMEM co-issue across
// independent waves (m114). Column sums: per-wave q-reduce + fire-and-forget
// device atomics (never waited until the end-of-kernel counter protocol).
// sim = xn @ xn^T, 2-term split-bf16: sim ~= (hiA+loA).hiB (drop A.loB ~2e-4).
// Pair scheduling: panel p + panel 63-p = 65 tiles, 13 blocks/pair -> every
// block EXACTLY 5 tiles; grid 416 x 512thr. loss = mean(log1p(sumP*sumN)).

#define NR    8192
#define DIMK  128
#define NT    64
#define NBLKS 416   // 32 pairs x 13 blocks, 5 tiles each

typedef __attribute__((ext_vector_type(8))) short short8;
typedef __attribute__((ext_vector_type(4))) float f32x4;

__device__ __forceinline__ unsigned short bf16_rne(float f) {
  uint32_t u = __float_as_uint(f);
  u += 0x7FFFu + ((u >> 16) & 1u);
  return (unsigned short)(u >> 16);
}

// ws: xhi bf16[NR*DIMK] (2MB) | xlo (2MB) | gP f32[NR] | gN f32[NR] | counter

__global__ __launch_bounds__(256) void normalize_split_kernel(
    const float* __restrict__ x, unsigned short* __restrict__ xhi,
    unsigned short* __restrict__ xlo, float* __restrict__ gP,
    float* __restrict__ gN, int* __restrict__ counter) {
  if (blockIdx.x < 32)      gP[blockIdx.x * 256 + threadIdx.x] = 0.f;
  else if (blockIdx.x < 64) gN[(blockIdx.x - 32) * 256 + threadIdx.x] = 0.f;
  if (blockIdx.x == 64 && threadIdx.x == 0) *counter = 0;

  const int wave = threadIdx.x >> 6;
  const int lane = threadIdx.x & 63;
  const int row  = blockIdx.x * 4 + wave;
  const float2 v = ((const float2*)(x + (size_t)row * DIMK))[lane];
  float ss = v.x * v.x + v.y * v.y;
  #pragma unroll
  for (int s = 1; s < 64; s <<= 1) ss += __shfl_xor(ss, s);
  const float r = rsqrtf(ss);
  const float a = v.x * r, b = v.y * r;
  const unsigned short ha = bf16_rne(a), hb = bf16_rne(b);
  const float haf = __uint_as_float((uint32_t)ha << 16);
  const float hbf = __uint_as_float((uint32_t)hb << 16);
  ushort2 hi, lo;
  hi.x = ha; hi.y = hb;
  lo.x = bf16_rne(a - haf); lo.y = bf16_rne(b - hbf);
  ((ushort2*)xhi)[(size_t)row * 64 + lane] = hi;
  ((ushort2*)xlo)[(size_t)row * 64 + lane] = lo;
}

__global__ __launch_bounds__(512, 2) void simloss_kernel(
    const unsigned short* __restrict__ xhi, const unsigned short* __restrict__ xlo,
    const int* __restrict__ tgt, float* __restrict__ gP, float* __restrict__ gN,
    int* __restrict__ counter, float* __restrict__ out) {
  __shared__ float red[512];
  __shared__ int islast;

  const int tid  = threadIdx.x;
  const int wave = tid >> 6, lane = tid & 63;
  const int wy = wave & 3, wx = wave >> 2;   // frag grid: 4 row-waves x 2 col-waves
  const int q = lane >> 4, mcol = lane & 15;

  // pair decode: 13 blocks per pair, 5 tiles each (65 = 13*5, exact)
  const int p  = blockIdx.x / 13;
  const int b  = blockIdx.x - p * 13;
  const int n1 = NT - p;           // tiles in panel1 (bi=p)
  const int p2 = NT - 1 - p;       // panel2 bi
  const int t0 = b * 5;

  short8 Ah[2][4], Al[2][4];
  int ta[2][4];
  float rowP[2][4], rowN[2][4];

  // direct global->register A fragments + targets for panel bi
  auto loadA = [&](int bi) {
    #pragma unroll
    for (int fr = 0; fr < 2; ++fr) {
      const int r = bi * 128 + wy * 32 + fr * 16 + mcol;
      const unsigned short* gh = xhi + (size_t)r * DIMK + q * 8;
      const unsigned short* gl = xlo + (size_t)r * DIMK + q * 8;
      #pragma unroll
      for (int ks = 0; ks < 4; ++ks) {
        Ah[fr][ks] = *(const short8*)(gh + ks * 32);
        Al[fr][ks] = *(const short8*)(gl + ks * 32);
      }
      #pragma unroll
      for (int rg = 0; rg < 4; ++rg)
        ta[fr][rg] = tgt[bi * 128 + wy * 32 + fr * 16 + q * 4 + rg];
    }
  };
  auto zeroRows = [&]() {
    #pragma unroll
    for (int fr = 0; fr < 2; ++fr)
      #pragma unroll
      for (int rg = 0; rg < 4; ++rg) { rowP[fr][rg] = 0.f; rowN[fr][rg] = 0.f; }
  };
  auto flushRows = [&](int bi) {
    #pragma unroll
    for (int fr = 0; fr < 2; ++fr)
      #pragma unroll
      for (int rg = 0; rg < 4; ++rg) {
        float vp = rowP[fr][rg], vn = rowN[fr][rg];
        #pragma unroll
        for (int m = 1; m < 16; m <<= 1) {
          vp += __shfl_xor(vp, m);
          vn += __shfl_xor(vn, m);
        }
        if (mcol == 0) {
          const int row = bi * 128 + wy * 32 + fr * 16 + q * 4 + rg;
          atomicAdd(&gP[row], vp);
          atomicAdd(&gN[row], vn);
        }
      }
  };

  int cur_bi = (t0 < n1) ? p : p2;
  loadA(cur_bi);
  zeroRows();

  for (int tl = 0; tl < 5; ++tl) {
    const int ix = t0 + tl;
    const int bi = (ix < n1) ? p : p2;
    const int bj = (ix < n1) ? p + ix : p2 + (ix - n1);

    if (bi != cur_bi) {          // at most one panel switch per block
      flushRows(cur_bi);
      zeroRows();
      cur_bi = bi;
      loadA(bi);
    }

    // ---- compute tile: B frags direct from global (L1/L2-hot) ----
    f32x4 acc[2][4];
    #pragma unroll
    for (int fr = 0; fr < 2; ++fr)
      #pragma unroll
      for (int fc = 0; fc < 4; ++fc)
        acc[fr][fc] = (f32x4){0.f, 0.f, 0.f, 0.f};

    #pragma unroll
    for (int ks = 0; ks < 4; ++ks) {
      short8 bh[4];
      #pragma unroll
      for (int fc = 0; fc < 4; ++fc) {
        const int rb = bj * 128 + wx * 64 + fc * 16 + mcol;
        bh[fc] = *(const short8*)(xhi + (size_t)rb * DIMK + ks * 32 + q * 8);
      }
      #pragma unroll
      for (int fc = 0; fc < 4; ++fc) {
        acc[0][fc] = __builtin_amdgcn_mfma_f32_16x16x32_bf16(Ah[0][ks], bh[fc], acc[0][fc], 0, 0, 0);
        acc[1][fc] = __builtin_amdgcn_mfma_f32_16x16x32_bf16(Ah[1][ks], bh[fc], acc[1][fc], 0, 0, 0);
        acc[0][fc] = __builtin_amdgcn_mfma_f32_16x16x32_bf16(Al[0][ks], bh[fc], acc[0][fc], 0, 0, 0);
        acc[1][fc] = __builtin_amdgcn_mfma_f32_16x16x32_bf16(Al[1][ks], bh[fc], acc[1][fc], 0, 0, 0);
      }
    }

    // ---- epilogue: C layout col = mcol, row = q*4 + reg ----
    int tb[4];
    #pragma unroll
    for (int fc = 0; fc < 4; ++fc)
      tb[fc] = tgt[bj * 128 + wx * 64 + fc * 16 + mcol];

    float cP[4] = {0.f, 0.f, 0.f, 0.f}, cN[4] = {0.f, 0.f, 0.f, 0.f};
    #pragma unroll
    for (int fr = 0; fr < 2; ++fr) {
      #pragma unroll
      for (int rg = 0; rg < 4; ++rg) {
        const int taa = ta[fr][rg];
        float vp = 0.f, vn = 0.f;
        #pragma unroll
        for (int fc = 0; fc < 4; ++fc) {
          const float s  = acc[fr][fc][rg];
          const bool pos = (taa == tb[fc]);
          const float ap = fmaxf(1.25f - s, 0.f);
          const float an = fmaxf(s - 0.25f, 0.f);
          const float arg = pos ? ap * fmaf(s, 64.f, -48.f) : an * an * 64.f;
          const float e = __expf(arg);
          const float ep = pos ? e : 0.f;
          const float en = pos ? 0.f : e;
          vp += ep; vn += en;
          cP[fc] += ep; cN[fc] += en;
        }
        rowP[fr][rg] += vp;
        rowN[fr][rg] += vn;
      }
    }

    // column sums -> transpose rows (off-diagonal tiles only), fire-and-forget
    if (bj != bi) {
      #pragma unroll
      for (int fc = 0; fc < 4; ++fc) {
        float a = cP[fc], bb = cN[fc];
        a  += __shfl_xor(a, 16);  a  += __shfl_xor(a, 32);
        bb += __shfl_xor(bb, 16); bb += __shfl_xor(bb, 32);
        if (q == 0) {
          const int col = bj * 128 + wx * 64 + fc * 16 + mcol;
          atomicAdd(&gP[col], a);
          atomicAdd(&gN[col], bb);
        }
      }
    }
  }
  flushRows(cur_bi);

  // ---- fence-free last-block finalize (R4-proven) ----
  __builtin_amdgcn_s_waitcnt(0);   // all my atomics ack'd before counter bump
  __syncthreads();
  if (tid == 0) islast = (atomicAdd(counter, 1) == NBLKS - 1) ? 1 : 0;
  __syncthreads();
  if (islast) {
    float local = 0.f;
    #pragma unroll 1
    for (int bb = 0; bb < 2; ++bb) {
      const int base = bb * 4096 + tid * 8;
      float pv[8], nv[8];
      #pragma unroll
      for (int u = 0; u < 8; ++u) pv[u] = atomicAdd(&gP[base + u], 0.0f);
      #pragma unroll
      for (int u = 0; u < 8; ++u) nv[u] = atomicAdd(&gN[base + u], 0.0f);
      #pragma unroll
      for (int u = 0; u < 8; ++u) local += log1pf(pv[u] * nv[u]);
    }
    red[tid] = local;
    __syncthreads();
    for (int s2 = 256; s2 > 0; s2 >>= 1) {
      if (tid < s2) red[tid] += red[tid + s2];
      __syncthreads();
    }
    if (tid == 0) out[0] = red[0] / (float)NR;
  }
}

extern "C" void kernel_launch(void* const* d_in, const int* in_sizes, int n_in,
                              void* d_out, int out_size, void* d_ws, size_t ws_size,
                              hipStream_t stream) {
  const float* x  = (const float*)d_in[0];
  const int* tgt  = (const int*)d_in[1];
  float* out      = (float*)d_out;

  unsigned short* xhi = (unsigned short*)d_ws;
  unsigned short* xlo = xhi + (size_t)NR * DIMK;
  float* gP = (float*)((char*)d_ws + (size_t)NR * DIMK * 4);
  float* gN = gP + NR;
  int* counter = (int*)(gN + NR);

  normalize_split_kernel<<<NR / 4, 256, 0, stream>>>(x, xhi, xlo, gP, gN, counter);
  simloss_kernel<<<NBLKS, 512, 0, stream>>>(xhi, xlo, tgt, gP, gN, counter, out);
}